// Round 2
// baseline (364.953 us; speedup 1.0000x reference)
//
#include <hip/hip_runtime.h>

// MultiKR rec-path, fully fused, FP32, single kernel.
//
// Structure: lane = sample (64 samples/block), 8 waves/block split the output
// columns of each matmul 8 ways. Activations live in per-lane VGPRs; weights
// are wave-uniform -> scalar loads (s_load) feeding v_fmac's SGPR operand.
// Inner loops are pure FMA issue (the fp32 roofline; no fp32 MFMA on CDNA4).
// LDS is used only for layer-boundary exchanges (output-split -> full vector)
// with bank-quad-safe padded layouts (68/132-float rows: <=2-way, free).
//
// grid = 256 blocks x 512 thr  -> 2048 waves = 2 waves/SIMD (launch_bounds 512,2).

constexpr int BTOT  = 16384;
constexpr int NWAVE = 8;

__global__ __launch_bounds__(512, 2) void multikr_fused(
    const int* __restrict__ user_id, const int* __restrict__ item_id,
    const float* __restrict__ rec_target,
    const float* __restrict__ user_emb, const float* __restrict__ item_emb,
    const float* __restrict__ entity_emb,
    const float* __restrict__ w_vv, const float* __restrict__ w_ev,
    const float* __restrict__ w_ve, const float* __restrict__ w_ee,
    const float* __restrict__ b_v, const float* __restrict__ b_e,
    const float* __restrict__ Wul, const float* __restrict__ bul,
    const float* __restrict__ W1, const float* __restrict__ b1,
    const float* __restrict__ W2, const float* __restrict__ b2,
    const float* __restrict__ W3, const float* __restrict__ b3,
    float* __restrict__ out)
{
    __shared__ __align__(16) float exS[64][68];    // 17.4 KB: user / h2-partial exchange
    __shared__ __align__(16) float exB[64][132];   // 33.8 KB: h1 exchange
    __shared__ float psum[NWAVE][64];              // 2 KB: output partial dots

    const int t    = threadIdx.x;
    const int lane = t & 63;
    const int wv   = __builtin_amdgcn_readfirstlane(t >> 6);  // force SGPR: scalar weight addressing
    const int s0   = blockIdx.x * 64;
    const int smp  = s0 + lane;
    const int j8   = wv * 8;    // this wave's 8-wide output slice (uMLP, h2)
    const int j16  = wv * 16;   // this wave's 16-wide output slice (h1)

    // ---------------- gather: full embedding rows into registers ----------------
    float u[64], it[64], hd[64];
    {
        const int uid = user_id[smp];
        const int iid = item_id[smp];
        const float4* ur = (const float4*)(user_emb   + (size_t)uid * 64);
        const float4* ir = (const float4*)(item_emb   + (size_t)iid * 64);
        const float4* er = (const float4*)(entity_emb + (size_t)iid * 64);
#pragma unroll
        for (int k = 0; k < 16; ++k) {
            const float4 a = ur[k];
            u[4*k] = a.x; u[4*k+1] = a.y; u[4*k+2] = a.z; u[4*k+3] = a.w;
            const float4 b = ir[k];
            it[4*k] = b.x; it[4*k+1] = b.y; it[4*k+2] = b.z; it[4*k+3] = b.w;
            const float4 c = er[k];
            hd[4*k] = c.x; hd[4*k+1] = c.y; hd[4*k+2] = c.z; hd[4*k+3] = c.w;
        }
    }
    const float bv = b_v[0], be = b_e[0];

    // ---------------- 2 x { user MLP (8-way split) ; cross&compress } ----------
#pragma unroll
    for (int layer = 0; layer < 2; ++layer) {
        // user = relu(user @ Wul + bul), this wave computes cols [j8, j8+8)
        float ua[8];
#pragma unroll
        for (int k = 0; k < 8; ++k) ua[k] = bul[j8 + k];
#pragma unroll
        for (int d = 0; d < 64; ++d) {
            const float* wr = Wul + d * 64 + j8;   // uniform -> s_load_dwordx8
            const float ud = u[d];
#pragma unroll
            for (int k = 0; k < 8; ++k) ua[k] = fmaf(ud, wr[k], ua[k]);
        }
        *(float4*)&exS[lane][j8]     = make_float4(fmaxf(ua[0],0.f), fmaxf(ua[1],0.f),
                                                   fmaxf(ua[2],0.f), fmaxf(ua[3],0.f));
        *(float4*)&exS[lane][j8 + 4] = make_float4(fmaxf(ua[4],0.f), fmaxf(ua[5],0.f),
                                                   fmaxf(ua[6],0.f), fmaxf(ua[7],0.f));

        // cross&compress (redundant in every wave; avoids 2 more exchanges)
        float dhv = 0.f, die = 0.f, dhe = 0.f, dee = 0.f;
#pragma unroll
        for (int d = 0; d < 64; ++d) {
            dhv = fmaf(hd[d], w_vv[d], dhv);   // head . w_vv
            die = fmaf(it[d], w_ev[d], die);   // item . w_ev
            dhe = fmaf(hd[d], w_ve[d], dhe);   // head . w_ve
            dee = fmaf(it[d], w_ee[d], dee);   // item . w_ee
        }
#pragma unroll
        for (int d = 0; d < 64; ++d) {
            const float iv = it[d], hv = hd[d];
            it[d] = fmaf(iv, dhv, fmaf(hv, die, bv));  // item' = i*(h.wvv) + h*(i.wev) + b_v
            hd[d] = fmaf(iv, dhe, fmaf(hv, dee, be));  // head' = i*(h.wve) + h*(i.wee) + b_e
        }
        __syncthreads();                                   // exS slices complete
#pragma unroll
        for (int q = 0; q < 16; ++q) {                     // read back full user vector
            const float4 v = *(const float4*)&exS[lane][4*q];
            u[4*q] = v.x; u[4*q+1] = v.y; u[4*q+2] = v.z; u[4*q+3] = v.w;
        }
        __syncthreads();                                   // exS safe to rewrite
    }

    // ---------------- h1 = relu([user|item] @ W1 + b1), 16 cols/wave ----------
    float h1a[16];
#pragma unroll
    for (int k = 0; k < 16; ++k) h1a[k] = b1[j16 + k];
#pragma unroll
    for (int d = 0; d < 64; ++d) {
        const float* wr = W1 + d * 128 + j16;              // s_load_dwordx16
        const float ud = u[d];
#pragma unroll
        for (int k = 0; k < 16; ++k) h1a[k] = fmaf(ud, wr[k], h1a[k]);
    }
#pragma unroll
    for (int d = 0; d < 64; ++d) {
        const float* wr = W1 + (64 + d) * 128 + j16;
        const float vd = it[d];
#pragma unroll
        for (int k = 0; k < 16; ++k) h1a[k] = fmaf(vd, wr[k], h1a[k]);
    }
#pragma unroll
    for (int q = 0; q < 4; ++q)
        *(float4*)&exB[lane][j16 + 4*q] =
            make_float4(fmaxf(h1a[4*q  ],0.f), fmaxf(h1a[4*q+1],0.f),
                        fmaxf(h1a[4*q+2],0.f), fmaxf(h1a[4*q+3],0.f));
    __syncthreads();
    float h1v[128];
#pragma unroll
    for (int q = 0; q < 32; ++q) {
        const float4 v = *(const float4*)&exB[lane][4*q];
        h1v[4*q] = v.x; h1v[4*q+1] = v.y; h1v[4*q+2] = v.z; h1v[4*q+3] = v.w;
    }

    // ---------------- h2 = relu(h1 @ W2 + b2), 8 cols/wave ---------------------
    float h2a[8];
#pragma unroll
    for (int k = 0; k < 8; ++k) h2a[k] = b2[j8 + k];
#pragma unroll
    for (int d = 0; d < 128; ++d) {
        const float* wr = W2 + d * 64 + j8;                // s_load_dwordx8
        const float vd = h1v[d];
#pragma unroll
        for (int k = 0; k < 8; ++k) h2a[k] = fmaf(vd, wr[k], h2a[k]);
    }

    // ---------------- out = relu(h2 @ W3 + b3): partial dot + LDS reduce -------
    float p = 0.f;
#pragma unroll
    for (int k = 0; k < 8; ++k) p = fmaf(fmaxf(h2a[k], 0.f), W3[j8 + k], p);
    psum[wv][lane] = p;
    __syncthreads();
    if (wv == 0) {
        float acc = b3[0];
#pragma unroll
        for (int pw = 0; pw < NWAVE; ++pw) acc += psum[pw][lane];
        out[smp] = fmaxf(acc, 0.f);
    } else if (wv == 1) {
        out[BTOT + smp] = rec_target[smp];                 // tuple output #2
    }
}

extern "C" void kernel_launch(void* const* d_in, const int* in_sizes, int n_in,
                              void* d_out, int out_size, void* d_ws, size_t ws_size,
                              hipStream_t stream) {
    (void)in_sizes; (void)n_in; (void)d_ws; (void)ws_size; (void)out_size;
    multikr_fused<<<BTOT / 64, 512, 0, stream>>>(
        (const int*)d_in[0],  (const int*)d_in[1],  (const float*)d_in[2],
        (const float*)d_in[3], (const float*)d_in[4], (const float*)d_in[5],
        (const float*)d_in[6], (const float*)d_in[7], (const float*)d_in[8],
        (const float*)d_in[9], (const float*)d_in[10], (const float*)d_in[11],
        (const float*)d_in[12], (const float*)d_in[13], (const float*)d_in[14],
        (const float*)d_in[15], (const float*)d_in[16], (const float*)d_in[17],
        (const float*)d_in[18], (const float*)d_in[19],
        (float*)d_out);
}

// Round 3
// 260.019 us; speedup vs baseline: 1.4036x; 1.4036x over previous
//
#include <hip/hip_runtime.h>

// MultiKR rec-path, fused, FP32.
// lane = output-col, activations transposed in LDS [dim][sample] (PAD=36),
// slab = 8 samples per wave -> 2048 waves total (2/SIMD), grid 512 x 256thr.
// uMLP weights staged in LDS; W1/W2 streamed from global (L2-resident) with an
// explicit double-buffered 4-d-group software pipeline (16/8 loads per group).

constexpr int BTOT = 16384;
constexpr int PAD  = 36;     // sample stride in floats (16B-aligned slabs)

__device__ __forceinline__ void ldg16(float* buf, const float* __restrict__ W,
                                      int dbase, int c0) {
#pragma unroll
    for (int k = 0; k < 4; ++k)
#pragma unroll
        for (int p = 0; p < 4; ++p)
            buf[4*k+p] = W[(dbase + k) * 128 + c0 + 32*p];
}
__device__ __forceinline__ void cmp16(float (&acc)[4][4], const float* buf,
                                      const float* smbase, int dbase, int aoff) {
#pragma unroll
    for (int k = 0; k < 4; ++k) {
        const float4 av = *(const float4*)(smbase + (dbase + k) * PAD + aoff);
#pragma unroll
        for (int p = 0; p < 4; ++p) {
            const float w = buf[4*k+p];
            acc[p][0] = fmaf(av.x, w, acc[p][0]);
            acc[p][1] = fmaf(av.y, w, acc[p][1]);
            acc[p][2] = fmaf(av.z, w, acc[p][2]);
            acc[p][3] = fmaf(av.w, w, acc[p][3]);
        }
    }
}
__device__ __forceinline__ void ldg8(float* buf, const float* __restrict__ W,
                                     int dbase, int c0) {
#pragma unroll
    for (int k = 0; k < 4; ++k)
#pragma unroll
        for (int p = 0; p < 2; ++p)
            buf[2*k+p] = W[(dbase + k) * 64 + c0 + 32*p];
}
__device__ __forceinline__ void cmp8(float (&acc)[2][4], const float* buf,
                                     const float* smbase, int dbase, int aoff) {
#pragma unroll
    for (int k = 0; k < 4; ++k) {
        const float4 av = *(const float4*)(smbase + (dbase + k) * PAD + aoff);
#pragma unroll
        for (int p = 0; p < 2; ++p) {
            const float w = buf[2*k+p];
            acc[p][0] = fmaf(av.x, w, acc[p][0]);
            acc[p][1] = fmaf(av.y, w, acc[p][1]);
            acc[p][2] = fmaf(av.z, w, acc[p][2]);
            acc[p][3] = fmaf(av.w, w, acc[p][3]);
        }
    }
}

__global__ __launch_bounds__(256, 2) void multikr_fused(
    const int* __restrict__ user_id, const int* __restrict__ item_id,
    const float* __restrict__ rec_target,
    const float* __restrict__ user_emb, const float* __restrict__ item_emb,
    const float* __restrict__ entity_emb,
    const float* __restrict__ w_vv, const float* __restrict__ w_ev,
    const float* __restrict__ w_ve, const float* __restrict__ w_ee,
    const float* __restrict__ b_v, const float* __restrict__ b_e,
    const float* __restrict__ Wul, const float* __restrict__ bul,
    const float* __restrict__ W1, const float* __restrict__ b1,
    const float* __restrict__ W2, const float* __restrict__ b2,
    const float* __restrict__ W3, const float* __restrict__ b3,
    float* __restrict__ out)
{
    // flat rows 0..63: user | 64..127: item | 128..191: head->h1lo | 192..255: spare->h1hi
    __shared__ __align__(16) float sm[4 * 64 * PAD];   // 36.9 KB
    __shared__ __align__(16) float sWul[64 * 64];      // 16 KB
    __shared__ __align__(16) float wcT[4][64];         // 1 KB
    __shared__ float scal[4][32];

    const int t    = threadIdx.x;
    const int lane = t & 63;
    const int wv   = t >> 6;           // wave 0..3 owns samples [8wv, 8wv+8)
    const int c0   = lane & 31;        // column base
    const int aoff = wv * 8 + 4 * (lane >> 5);   // this lane's 4-sample group
    const int s0   = blockIdx.x * 32;

    float* U  = sm;                 // rows 0..63
    float* IT = sm + 64 * PAD;      // rows 64..127
    float* HD = sm + 128 * PAD;     // rows 128..191
    float* SP = sm + 192 * PAD;     // rows 192..255

    // ---------------- gather + stage ----------------------------------------
    {
        const int s = t & 31, part = t >> 3 >> 2;        // part = t>>5, 0..7
        const int uid = user_id[s0 + s], iid = item_id[s0 + s];
        const float4* ur = (const float4*)(user_emb   + (size_t)uid * 64 + part * 8);
        const float4* ir = (const float4*)(item_emb   + (size_t)iid * 64 + part * 8);
        const float4* er = (const float4*)(entity_emb + (size_t)iid * 64 + part * 8);
        const float4 u0 = ur[0], u1 = ur[1];
        const float4 i0 = ir[0], i1 = ir[1];
        const float4 e0 = er[0], e1 = er[1];
        const int db = part * 8;
        U[(db+0)*PAD+s]=u0.x; U[(db+1)*PAD+s]=u0.y; U[(db+2)*PAD+s]=u0.z; U[(db+3)*PAD+s]=u0.w;
        U[(db+4)*PAD+s]=u1.x; U[(db+5)*PAD+s]=u1.y; U[(db+6)*PAD+s]=u1.z; U[(db+7)*PAD+s]=u1.w;
        IT[(db+0)*PAD+s]=i0.x; IT[(db+1)*PAD+s]=i0.y; IT[(db+2)*PAD+s]=i0.z; IT[(db+3)*PAD+s]=i0.w;
        IT[(db+4)*PAD+s]=i1.x; IT[(db+5)*PAD+s]=i1.y; IT[(db+6)*PAD+s]=i1.z; IT[(db+7)*PAD+s]=i1.w;
        HD[(db+0)*PAD+s]=e0.x; HD[(db+1)*PAD+s]=e0.y; HD[(db+2)*PAD+s]=e0.z; HD[(db+3)*PAD+s]=e0.w;
        HD[(db+4)*PAD+s]=e1.x; HD[(db+5)*PAD+s]=e1.y; HD[(db+6)*PAD+s]=e1.z; HD[(db+7)*PAD+s]=e1.w;
        const float4* wg = (const float4*)Wul;
        float4*       ws = (float4*)sWul;
#pragma unroll
        for (int i = 0; i < 4; ++i) ws[i * 256 + t] = wg[i * 256 + t];
        if (t < 64) {
            wcT[0][t] = w_vv[t]; wcT[1][t] = w_ev[t];
            wcT[2][t] = w_ve[t]; wcT[3][t] = w_ee[t];
        }
    }
    __syncthreads();
    const float bv = b_v[0], be = b_e[0];

    // ---------------- 2 x { user MLP + cross dots ; cross update } -----------
#pragma unroll
    for (int layer = 0; layer < 2; ++layer) {
        const float* ub = (layer == 0) ? U : SP;
        float*       vb = (layer == 0) ? SP : U;
        {   // user' cols {c0, c0+32} x 4 samples
            float a0[4], a1[4];
            const float bb0 = bul[c0], bb1 = bul[c0 + 32];
#pragma unroll
            for (int i = 0; i < 4; ++i) { a0[i] = bb0; a1[i] = bb1; }
#pragma unroll 4
            for (int d = 0; d < 64; ++d) {
                const float4 av = *(const float4*)(ub + d * PAD + aoff);
                const float w0 = sWul[d * 64 + c0];
                const float w1 = sWul[d * 64 + c0 + 32];
                a0[0]=fmaf(av.x,w0,a0[0]); a0[1]=fmaf(av.y,w0,a0[1]);
                a0[2]=fmaf(av.z,w0,a0[2]); a0[3]=fmaf(av.w,w0,a0[3]);
                a1[0]=fmaf(av.x,w1,a1[0]); a1[1]=fmaf(av.y,w1,a1[1]);
                a1[2]=fmaf(av.z,w1,a1[2]); a1[3]=fmaf(av.w,w1,a1[3]);
            }
            *(float4*)(vb + c0 * PAD + aoff) =
                make_float4(fmaxf(a0[0],0.f), fmaxf(a0[1],0.f), fmaxf(a0[2],0.f), fmaxf(a0[3],0.f));
            *(float4*)(vb + (c0 + 32) * PAD + aoff) =
                make_float4(fmaxf(a1[0],0.f), fmaxf(a1[1],0.f), fmaxf(a1[2],0.f), fmaxf(a1[3],0.f));
        }
        // cross dots: scal[0]=h.wvv scal[1]=i.wev scal[2]=h.wve scal[3]=i.wee
        if (t < 128) {
            const int which = t >> 5;          // 0..3
            const int scol  = t & 31;
            const float* src = (which & 1) ? IT : HD;
            float a = 0.f;
#pragma unroll
            for (int dq = 0; dq < 16; ++dq) {
                const float4 w = *(const float4*)&wcT[which][4 * dq];
                a = fmaf(src[(4*dq+0)*PAD + scol], w.x, a);
                a = fmaf(src[(4*dq+1)*PAD + scol], w.y, a);
                a = fmaf(src[(4*dq+2)*PAD + scol], w.z, a);
                a = fmaf(src[(4*dq+3)*PAD + scol], w.w, a);
            }
            scal[which][scol] = a;
        }
        __syncthreads();
        {   // elementwise update: thread = (dim d, 8-sample group q)
            const int d = t & 63, q = t >> 6;
            float* ip = IT + d * PAD + q * 8;
            float* hp = HD + d * PAD + q * 8;
            const float4 iv0 = *(const float4*)(ip),  iv1 = *(const float4*)(ip + 4);
            const float4 hv0 = *(const float4*)(hp),  hv1 = *(const float4*)(hp + 4);
            const float4 sa0 = *(const float4*)&scal[0][q*8], sa0b = *(const float4*)&scal[0][q*8+4];
            const float4 sb0 = *(const float4*)&scal[1][q*8], sb0b = *(const float4*)&scal[1][q*8+4];
            *(float4*)(ip) = make_float4(
                fmaf(iv0.x, sa0.x,  fmaf(hv0.x, sb0.x,  bv)),
                fmaf(iv0.y, sa0.y,  fmaf(hv0.y, sb0.y,  bv)),
                fmaf(iv0.z, sa0.z,  fmaf(hv0.z, sb0.z,  bv)),
                fmaf(iv0.w, sa0.w,  fmaf(hv0.w, sb0.w,  bv)));
            *(float4*)(ip + 4) = make_float4(
                fmaf(iv1.x, sa0b.x, fmaf(hv1.x, sb0b.x, bv)),
                fmaf(iv1.y, sa0b.y, fmaf(hv1.y, sb0b.y, bv)),
                fmaf(iv1.z, sa0b.z, fmaf(hv1.z, sb0b.z, bv)),
                fmaf(iv1.w, sa0b.w, fmaf(hv1.w, sb0b.w, bv)));
            if (layer == 0) {   // head only needed for next layer's dots
                const float4 sc0 = *(const float4*)&scal[2][q*8], sc0b = *(const float4*)&scal[2][q*8+4];
                const float4 sd0 = *(const float4*)&scal[3][q*8], sd0b = *(const float4*)&scal[3][q*8+4];
                *(float4*)(hp) = make_float4(
                    fmaf(iv0.x, sc0.x,  fmaf(hv0.x, sd0.x,  be)),
                    fmaf(iv0.y, sc0.y,  fmaf(hv0.y, sd0.y,  be)),
                    fmaf(iv0.z, sc0.z,  fmaf(hv0.z, sd0.z,  be)),
                    fmaf(iv0.w, sc0.w,  fmaf(hv0.w, sd0.w,  be)));
                *(float4*)(hp + 4) = make_float4(
                    fmaf(iv1.x, sc0b.x, fmaf(hv1.x, sd0b.x, be)),
                    fmaf(iv1.y, sc0b.y, fmaf(hv1.y, sd0b.y, be)),
                    fmaf(iv1.z, sc0b.z, fmaf(hv1.z, sd0b.z, be)),
                    fmaf(iv1.w, sc0b.w, fmaf(hv1.w, sd0b.w, be)));
            }
        }
        __syncthreads();
    }
    // user final in U (rows 0..63), item final in IT (rows 64..127).

    // ---------------- h1 = relu([user|item] @ W1 + b1), pipelined ------------
    {
        float acc[4][4];
#pragma unroll
        for (int p = 0; p < 4; ++p) {
            const float bb = b1[c0 + 32 * p];
#pragma unroll
            for (int i = 0; i < 4; ++i) acc[p][i] = bb;
        }
        float wA[16], wB[16];
        ldg16(wA, W1, 0, c0);
        for (int gi = 0; gi < 16; ++gi) {       // 32 groups of 4 d (d: 0..127 over U,IT)
            ldg16(wB, W1, 4 * (2 * gi + 1), c0);
            cmp16(acc, wA, sm, 4 * (2 * gi), aoff);
            if (gi < 15) ldg16(wA, W1, 4 * (2 * gi + 2), c0);
            cmp16(acc, wB, sm, 4 * (2 * gi + 1), aoff);
        }
#pragma unroll
        for (int p = 0; p < 4; ++p) {           // h1 row j=c0+32p -> flat rows 128..255
            float* dst = sm + (128 + c0 + 32 * p) * PAD + aoff;
            *(float4*)dst = make_float4(fmaxf(acc[p][0],0.f), fmaxf(acc[p][1],0.f),
                                        fmaxf(acc[p][2],0.f), fmaxf(acc[p][3],0.f));
        }
    }
    __syncthreads();

    // ---------------- h2 = relu(h1 @ W2 + b2), pipelined ---------------------
    {
        float acc[2][4];
#pragma unroll
        for (int p = 0; p < 2; ++p) {
            const float bb = b2[c0 + 32 * p];
#pragma unroll
            for (int i = 0; i < 4; ++i) acc[p][i] = bb;
        }
        const float* h1b = sm + 128 * PAD;      // h1 rows
        float wA[8], wB[8];
        ldg8(wA, W2, 0, c0);
        for (int gi = 0; gi < 16; ++gi) {       // 32 groups of 4 d (d: 0..127)
            ldg8(wB, W2, 4 * (2 * gi + 1), c0);
            cmp8(acc, wA, h1b, 4 * (2 * gi), aoff);
            if (gi < 15) ldg8(wA, W2, 4 * (2 * gi + 2), c0);
            cmp8(acc, wB, h1b, 4 * (2 * gi + 1), aoff);
        }
#pragma unroll
        for (int p = 0; p < 2; ++p) {           // h2 row j -> flat rows 0..63
            float* dst = sm + (c0 + 32 * p) * PAD + aoff;
            *(float4*)dst = make_float4(fmaxf(acc[p][0],0.f), fmaxf(acc[p][1],0.f),
                                        fmaxf(acc[p][2],0.f), fmaxf(acc[p][3],0.f));
        }
    }
    __syncthreads();

    // ---------------- out = relu(h2 @ W3 + b3) + rec_target pass-through -----
    if (t < 64) {
        const int s = t & 31, dh = t >> 5;
        float acc = 0.f;
#pragma unroll
        for (int k = 0; k < 32; ++k) {
            const int d = 32 * dh + k;
            acc = fmaf(sm[d * PAD + s], W3[d], acc);
        }
        acc += __shfl_xor(acc, 32);
        if (t < 32) out[s0 + s] = fmaxf(acc + b3[0], 0.f);
    } else if (t < 96) {
        const int s = t & 31;
        out[BTOT + s0 + s] = rec_target[s0 + s];
    }
}

extern "C" void kernel_launch(void* const* d_in, const int* in_sizes, int n_in,
                              void* d_out, int out_size, void* d_ws, size_t ws_size,
                              hipStream_t stream) {
    (void)in_sizes; (void)n_in; (void)d_ws; (void)ws_size; (void)out_size;
    multikr_fused<<<BTOT / 32, 256, 0, stream>>>(
        (const int*)d_in[0],  (const int*)d_in[1],  (const float*)d_in[2],
        (const float*)d_in[3], (const float*)d_in[4], (const float*)d_in[5],
        (const float*)d_in[6], (const float*)d_in[7], (const float*)d_in[8],
        (const float*)d_in[9], (const float*)d_in[10], (const float*)d_in[11],
        (const float*)d_in[12], (const float*)d_in[13], (const float*)d_in[14],
        (const float*)d_in[15], (const float*)d_in[16], (const float*)d_in[17],
        (const float*)d_in[18], (const float*)d_in[19],
        (float*)d_out);
}

// Round 4
// 258.907 us; speedup vs baseline: 1.4096x; 1.0043x over previous
//
#include <hip/hip_runtime.h>

// MultiKR rec-path, fused, FP32.
// lane = output-col (col==lane), activations transposed in LDS [dim][sample],
// PAD=20, 16 samples/block -> grid 1024 -> 4 blocks/CU (4 waves/SIMD).
// Each wave owns a 4-sample slab (aoff=4*wv); act reads are half/full-wave
// uniform 16B broadcasts (near-free in LDS). uMLP weights staged in LDS;
// W1/W2 streamed from global (L2-resident) with depth-1 double-buffered
// 8-d-group pipeline; 4 waves/SIMD hide the residual latency.

constexpr int BTOT = 16384;
constexpr int SPB  = 16;
constexpr int PAD  = 20;    // sample stride (floats): 16B-aligned float4 slabs

__global__ __launch_bounds__(256, 4) void multikr_fused(
    const int* __restrict__ user_id, const int* __restrict__ item_id,
    const float* __restrict__ rec_target,
    const float* __restrict__ user_emb, const float* __restrict__ item_emb,
    const float* __restrict__ entity_emb,
    const float* __restrict__ w_vv, const float* __restrict__ w_ev,
    const float* __restrict__ w_ve, const float* __restrict__ w_ee,
    const float* __restrict__ b_v, const float* __restrict__ b_e,
    const float* __restrict__ Wul, const float* __restrict__ bul,
    const float* __restrict__ W1, const float* __restrict__ b1,
    const float* __restrict__ W2, const float* __restrict__ b2,
    const float* __restrict__ W3, const float* __restrict__ b3,
    float* __restrict__ out)
{
    // rows 0..63: user | 64..127: item | 128..191: head -> h1[0:64) | 192..255: user' -> h1[64:128)
    __shared__ __align__(16) float sm[256 * PAD];     // 20 KB
    __shared__ __align__(16) float sWul[64 * 64];     // 16 KB
    __shared__ __align__(16) float wcT[4][64];        // 1 KB
    __shared__ __align__(16) float scal[4][SPB];

    const int t    = threadIdx.x;
    const int lane = t & 63;
    const int wv   = t >> 6;          // wave 0..3 owns samples [4wv, 4wv+4)
    const int aoff = wv << 2;
    const int s0   = blockIdx.x * SPB;

    float* U  = sm;                   // rows 0..63
    float* IT = sm + 64 * PAD;        // rows 64..127
    float* HD = sm + 128 * PAD;       // rows 128..191
    float* SP = sm + 192 * PAD;       // rows 192..255

    // ---------------- gather + stage -----------------------------------------
    {
        const int s = t & 15, part = t >> 4;          // part 0..15 -> dims [4p,4p+4)
        const int uid = user_id[s0 + s], iid = item_id[s0 + s];
        const float4 u4 = *((const float4*)(user_emb   + (size_t)uid * 64) + part);
        const float4 i4 = *((const float4*)(item_emb   + (size_t)iid * 64) + part);
        const float4 e4 = *((const float4*)(entity_emb + (size_t)iid * 64) + part);
        const int db = part << 2;
        U [(db+0)*PAD+s]=u4.x; U [(db+1)*PAD+s]=u4.y; U [(db+2)*PAD+s]=u4.z; U [(db+3)*PAD+s]=u4.w;
        IT[(db+0)*PAD+s]=i4.x; IT[(db+1)*PAD+s]=i4.y; IT[(db+2)*PAD+s]=i4.z; IT[(db+3)*PAD+s]=i4.w;
        HD[(db+0)*PAD+s]=e4.x; HD[(db+1)*PAD+s]=e4.y; HD[(db+2)*PAD+s]=e4.z; HD[(db+3)*PAD+s]=e4.w;
        const float4* wg = (const float4*)Wul;
        float4*       ws = (float4*)sWul;
#pragma unroll
        for (int i = 0; i < 4; ++i) ws[i * 256 + t] = wg[i * 256 + t];
        if (t < 64) { wcT[0][t]=w_vv[t]; wcT[1][t]=w_ev[t]; wcT[2][t]=w_ve[t]; wcT[3][t]=w_ee[t]; }
    }
    __syncthreads();
    const float bv = b_v[0], be = b_e[0];

    // ---------------- 2 x { user MLP + cross dots ; cross update } -----------
#pragma unroll
    for (int layer = 0; layer < 2; ++layer) {
        const float* ub = (layer == 0) ? U : SP;
        float*       vb = (layer == 0) ? SP : U;
        {   // user' col = lane, 4 samples
            float ua[4];
            const float bb = bul[lane];
#pragma unroll
            for (int i = 0; i < 4; ++i) ua[i] = bb;
#pragma unroll 8
            for (int d = 0; d < 64; ++d) {
                const float w = sWul[d * 64 + lane];
                const float4 av = *(const float4*)(ub + d * PAD + aoff);
                ua[0]=fmaf(av.x,w,ua[0]); ua[1]=fmaf(av.y,w,ua[1]);
                ua[2]=fmaf(av.z,w,ua[2]); ua[3]=fmaf(av.w,w,ua[3]);
            }
            *(float4*)(vb + lane * PAD + aoff) =
                make_float4(fmaxf(ua[0],0.f),fmaxf(ua[1],0.f),fmaxf(ua[2],0.f),fmaxf(ua[3],0.f));
        }
        // cross dots: wave wv computes scal[wv][*]; 0:h.wvv 1:i.wev 2:h.wve 3:i.wee
        if (lane < 16) {
            const float* src = (wv & 1) ? IT : HD;
            float a = 0.f;
#pragma unroll
            for (int dq = 0; dq < 16; ++dq) {
                const float4 w = *(const float4*)&wcT[wv][dq << 2];
                a = fmaf(src[(4*dq+0)*PAD + lane], w.x, a);
                a = fmaf(src[(4*dq+1)*PAD + lane], w.y, a);
                a = fmaf(src[(4*dq+2)*PAD + lane], w.z, a);
                a = fmaf(src[(4*dq+3)*PAD + lane], w.w, a);
            }
            scal[wv][lane] = a;
        }
        __syncthreads();
        {   // elementwise update: d = lane, this wave's 4 samples
            float* ip = IT + lane * PAD + aoff;
            float* hp = HD + lane * PAD + aoff;
            const float4 iv = *(const float4*)ip;
            const float4 hv = *(const float4*)hp;
            const float4 sa = *(const float4*)&scal[0][aoff];
            const float4 sb = *(const float4*)&scal[1][aoff];
            *(float4*)ip = make_float4(
                fmaf(iv.x, sa.x, fmaf(hv.x, sb.x, bv)),
                fmaf(iv.y, sa.y, fmaf(hv.y, sb.y, bv)),
                fmaf(iv.z, sa.z, fmaf(hv.z, sb.z, bv)),
                fmaf(iv.w, sa.w, fmaf(hv.w, sb.w, bv)));
            if (layer == 0) {      // head only needed for layer-2 dots
                const float4 sc = *(const float4*)&scal[2][aoff];
                const float4 sd = *(const float4*)&scal[3][aoff];
                *(float4*)hp = make_float4(
                    fmaf(iv.x, sc.x, fmaf(hv.x, sd.x, be)),
                    fmaf(iv.y, sc.y, fmaf(hv.y, sd.y, be)),
                    fmaf(iv.z, sc.z, fmaf(hv.z, sd.z, be)),
                    fmaf(iv.w, sc.w, fmaf(hv.w, sd.w, be)));
            }
        }
        __syncthreads();
    }
    // user final rows 0..63, item final rows 64..127.

    // ---------------- h1 = relu([user|item] @ W1 + b1): cols {lane, lane+64} --
    {
        float acc0[4], acc1[4];
        const float bb0 = b1[lane], bb1 = b1[lane + 64];
#pragma unroll
        for (int i = 0; i < 4; ++i) { acc0[i] = bb0; acc1[i] = bb1; }
        float wA[16], wB[16];
        auto ldg = [&](float* buf, int dbase) {
#pragma unroll
            for (int k = 0; k < 8; ++k) {
                buf[2*k]   = W1[(dbase + k) * 128 + lane];
                buf[2*k+1] = W1[(dbase + k) * 128 + lane + 64];
            }
        };
        auto cmp = [&](const float* buf, int dbase) {
#pragma unroll
            for (int k = 0; k < 8; ++k) {
                const float4 av = *(const float4*)(sm + (dbase + k) * PAD + aoff);
                const float w0 = buf[2*k], w1 = buf[2*k+1];
                acc0[0]=fmaf(av.x,w0,acc0[0]); acc0[1]=fmaf(av.y,w0,acc0[1]);
                acc0[2]=fmaf(av.z,w0,acc0[2]); acc0[3]=fmaf(av.w,w0,acc0[3]);
                acc1[0]=fmaf(av.x,w1,acc1[0]); acc1[1]=fmaf(av.y,w1,acc1[1]);
                acc1[2]=fmaf(av.z,w1,acc1[2]); acc1[3]=fmaf(av.w,w1,acc1[3]);
            }
        };
        ldg(wA, 0);
#pragma unroll
        for (int g = 0; g < 8; ++g) {            // 16 groups of 8 d over [0,128)
            ldg(wB, 16*g + 8);
            cmp(wA, 16*g);
            if (g < 7) ldg(wA, 16*g + 16);
            cmp(wB, 16*g + 8);
        }
        *(float4*)(sm + (128 + lane) * PAD + aoff) =
            make_float4(fmaxf(acc0[0],0.f),fmaxf(acc0[1],0.f),fmaxf(acc0[2],0.f),fmaxf(acc0[3],0.f));
        *(float4*)(sm + (192 + lane) * PAD + aoff) =
            make_float4(fmaxf(acc1[0],0.f),fmaxf(acc1[1],0.f),fmaxf(acc1[2],0.f),fmaxf(acc1[3],0.f));
    }
    __syncthreads();

    // ---------------- h2 = relu(h1 @ W2 + b2): col = lane ---------------------
    {
        float acc[4];
        const float bb = b2[lane];
#pragma unroll
        for (int i = 0; i < 4; ++i) acc[i] = bb;
        float wA[8], wB[8];
        auto ldg = [&](float* buf, int dbase) {
#pragma unroll
            for (int k = 0; k < 8; ++k) buf[k] = W2[(dbase + k) * 64 + lane];
        };
        auto cmp = [&](const float* buf, int dbase) {
#pragma unroll
            for (int k = 0; k < 8; ++k) {
                const float4 av = *(const float4*)(sm + (128 + dbase + k) * PAD + aoff);
                const float w = buf[k];
                acc[0]=fmaf(av.x,w,acc[0]); acc[1]=fmaf(av.y,w,acc[1]);
                acc[2]=fmaf(av.z,w,acc[2]); acc[3]=fmaf(av.w,w,acc[3]);
            }
        };
        ldg(wA, 0);
#pragma unroll
        for (int g = 0; g < 8; ++g) {            // 16 groups of 8 d over [0,128)
            ldg(wB, 16*g + 8);
            cmp(wA, 16*g);
            if (g < 7) ldg(wA, 16*g + 16);
            cmp(wB, 16*g + 8);
        }
        *(float4*)(sm + lane * PAD + aoff) =     // h2 -> rows 0..63
            make_float4(fmaxf(acc[0],0.f),fmaxf(acc[1],0.f),fmaxf(acc[2],0.f),fmaxf(acc[3],0.f));
    }
    __syncthreads();

    // ---------------- out = relu(h2 @ W3 + b3) + rec_target -------------------
    if (t < 64) {
        const int s = t & 15, dh = t >> 4;       // 4 chunks of 16 dims
        float acc = 0.f;
#pragma unroll
        for (int k = 0; k < 16; ++k) {
            const int d = 16 * dh + k;
            acc = fmaf(sm[d * PAD + s], W3[d], acc);
        }
        acc += __shfl_xor(acc, 16);
        acc += __shfl_xor(acc, 32);
        if (dh == 0) out[s0 + s] = fmaxf(acc + b3[0], 0.f);
    } else if (t < 80) {
        const int s = t - 64;
        out[BTOT + s0 + s] = rec_target[s0 + s];
    }
}

extern "C" void kernel_launch(void* const* d_in, const int* in_sizes, int n_in,
                              void* d_out, int out_size, void* d_ws, size_t ws_size,
                              hipStream_t stream) {
    (void)in_sizes; (void)n_in; (void)d_ws; (void)ws_size; (void)out_size;
    multikr_fused<<<BTOT / SPB, 256, 0, stream>>>(
        (const int*)d_in[0],  (const int*)d_in[1],  (const float*)d_in[2],
        (const float*)d_in[3], (const float*)d_in[4], (const float*)d_in[5],
        (const float*)d_in[6], (const float*)d_in[7], (const float*)d_in[8],
        (const float*)d_in[9], (const float*)d_in[10], (const float*)d_in[11],
        (const float*)d_in[12], (const float*)d_in[13], (const float*)d_in[14],
        (const float*)d_in[15], (const float*)d_in[16], (const float*)d_in[17],
        (const float*)d_in[18], (const float*)d_in[19],
        (float*)d_out);
}